// Round 17
// baseline (210.677 us; speedup 1.0000x reference)
//
#include <hip/hip_runtime.h>
#include <hip/hip_bf16.h>

typedef __bf16 bf16;
typedef __bf16 bf16x8 __attribute__((ext_vector_type(8)));
typedef __bf16 bf16x4 __attribute__((ext_vector_type(4)));
typedef float f32x4 __attribute__((ext_vector_type(4)));

#define HIDDEN 2048
#define SEQ 2048
#define NH 16
#define QL 1536
#define KVL 512
// 1/sqrt(192) * log2(e)
#define SCALE_LOG2E 0.10411754631f

// ---- global -> LDS direct load, 16B per lane. Dest = wave-uniform base + lane*16. ----
__device__ __forceinline__ void gload_lds16(const void* g, void* l) {
  typedef const __attribute__((address_space(1))) void* gp_t;
  typedef __attribute__((address_space(3))) void* lp_t;
  __builtin_amdgcn_global_load_lds((gp_t)(unsigned long long)g,
                                   (lp_t)(unsigned int)(unsigned long long)l, 16, 0, 0);
}

// raw v_exp_f32: computes 2^x
__device__ __forceinline__ float fexp2(float x) {
  float r; asm("v_exp_f32 %0, %1" : "=v"(r) : "v"(x)); return r;
}
// pack 2 f32 -> 2 bf16 in one u32 (low = lo)
__device__ __forceinline__ unsigned cvt_pk_bf16(float lo, float hi) {
  unsigned r; asm("v_cvt_pk_bf16_f32 %0, %1, %2" : "=v"(r) : "v"(lo), "v"(hi)); return r;
}

// ================= prep: 5 weight transposes (fp32[K][N] -> bf16[N][K]) + hidden cvt =================
__global__ void k_prep(const float* __restrict__ hidden, bf16* __restrict__ Xb,
                       const float* __restrict__ Wqa, bf16* __restrict__ WqaT,
                       const float* __restrict__ Wqb, bf16* __restrict__ WqbT,
                       const float* __restrict__ Wkva, bf16* __restrict__ WkvaT,
                       const float* __restrict__ Wkvb, bf16* __restrict__ WkvbT,
                       const float* __restrict__ Wo, bf16* __restrict__ WoT) {
  __shared__ float tile[32][33];
  int b = blockIdx.x, tid = threadIdx.x;
  const float* W; bf16* Wt; int K, N, bx, by;
  if (b < 3072)       { W = Wqa;  Wt = WqaT;  K = 2048; N = 1536; int r = b;         bx = r % 48;  by = r / 48; }
  else if (b < 7680)  { W = Wqb;  Wt = WqbT;  K = 1536; N = 3072; int r = b - 3072;  bx = r % 96;  by = r / 96; }
  else if (b < 8832)  { W = Wkva; Wt = WkvaT; K = 2048; N = 576;  int r = b - 7680;  bx = r % 18;  by = r / 18; }
  else if (b < 10880) { W = Wkvb; Wt = WkvbT; K = 512;  N = 4096; int r = b - 8832;  bx = r % 128; by = r / 128; }
  else if (b < 14976) { W = Wo;   Wt = WoT;   K = 2048; N = 2048; int r = b - 10880; bx = r % 64;  by = r / 64; }
  else {
    int r = b - 14976;
    int base = (r * 256 + tid) * 4;
    float4 v = *(const float4*)(hidden + base);
    bf16x4 o = { (bf16)v.x, (bf16)v.y, (bf16)v.z, (bf16)v.w };
    *(bf16x4*)(Xb + base) = o;
    return;
  }
  int n0 = bx * 32, k0 = by * 32, cc = tid & 31, rr = tid >> 5;
#pragma unroll
  for (int it = 0; it < 4; ++it) {
    int r = it * 8 + rr;
    tile[r][cc] = W[(size_t)(k0 + r) * N + n0 + cc];
  }
  __syncthreads();
#pragma unroll
  for (int it = 0; it < 4; ++it) {
    int r = it * 8 + rr;
    Wt[(size_t)(n0 + r) * K + k0 + cc] = (bf16)tile[cc][r];
  }
}

// ================= GEMM epilogue (shared) =================
__device__ __forceinline__ void gemm_epilogue(f32x4 acc[4][4], bf16* Cb, float* Cf,
                                              int N, int m0, int n0) {
  int lane = threadIdx.x & 63, w = threadIdx.x >> 6;
  int wr = w >> 1, wc = w & 1;
  int l15 = lane & 15, l4 = lane >> 4;
#pragma unroll
  for (int m = 0; m < 4; ++m)
#pragma unroll
    for (int n = 0; n < 4; ++n)
#pragma unroll
      for (int r = 0; r < 4; ++r) {
        int grow = m0 + wr * 64 + m * 16 + l4 * 4 + r;
        int gcol = n0 + wc * 64 + n * 16 + l15;
        if (gcol < N) {
          float v = acc[m][n][r];
          if (Cf) Cf[(size_t)grow * N + gcol] = v;
          else Cb[(size_t)grow * N + gcol] = (bf16)v;
        }
      }
}

// ================= GEMM body (m97 structure, single-buffered) — for well-occupied grids =================
__device__ __forceinline__ void gemm_body(const bf16* __restrict__ A, const bf16* __restrict__ Bt,
                                          bf16* __restrict__ Cb, float* __restrict__ Cf,
                                          int N, int Kfull, int kbase, int Klen,
                                          int m0, int n0, bf16* As, bf16* Bs) {
  int tid = threadIdx.x, lane = tid & 63, w = tid >> 6;
  int wr = w >> 1, wc = w & 1;
  int l15 = lane & 15, l4 = lane >> 4;
  f32x4 acc[4][4] = {};
  for (int k0 = kbase; k0 < kbase + Klen; k0 += 64) {
#pragma unroll
    for (int i = 0; i < 4; ++i) {
      int c = w * 4 + i;
      int row = c * 8 + (lane >> 3);
      int col = (lane & 7) * 8;
      gload_lds16(&A[(size_t)(m0 + row) * Kfull + k0 + col], &As[c * 512]);
      gload_lds16(&Bt[(size_t)(n0 + row) * Kfull + k0 + col], &Bs[c * 512]);
    }
    __syncthreads();
#pragma unroll
    for (int kk = 0; kk < 2; ++kk) {
      bf16x8 af[4], bfr[4];
#pragma unroll
      for (int m = 0; m < 4; ++m)
        af[m] = *(const bf16x8*)&As[(wr * 64 + m * 16 + l15) * 64 + kk * 32 + l4 * 8];
#pragma unroll
      for (int n = 0; n < 4; ++n)
        bfr[n] = *(const bf16x8*)&Bs[(wc * 64 + n * 16 + l15) * 64 + kk * 32 + l4 * 8];
      __builtin_amdgcn_s_setprio(1);
#pragma unroll
      for (int m = 0; m < 4; ++m)
#pragma unroll
        for (int n = 0; n < 4; ++n)
          acc[m][n] = __builtin_amdgcn_mfma_f32_16x16x32_bf16(af[m], bfr[n], acc[m][n], 0, 0, 0);
      __builtin_amdgcn_s_setprio(0);
    }
    __syncthreads();
  }
  gemm_epilogue(acc, Cb, Cf, N, m0, n0);
}

// ================= GEMM body, double-buffered prefetch (T3-min) — for grid-starved kernels =================
__device__ __forceinline__ void gemm_body_pf(const bf16* __restrict__ A, const bf16* __restrict__ Bt,
                                             bf16* __restrict__ Cb, float* __restrict__ Cf,
                                             int N, int Kfull, int kbase, int Klen,
                                             int m0, int n0, bf16* AsD, bf16* BsD) {
  int tid = threadIdx.x, lane = tid & 63, w = tid >> 6;
  int wr = w >> 1, wc = w & 1;
  int l15 = lane & 15, l4 = lane >> 4;
  f32x4 acc[4][4] = {};

  auto STAGE = [&](int buf, int k0) {
#pragma unroll
    for (int i = 0; i < 4; ++i) {
      int c = w * 4 + i;
      int row = c * 8 + (lane >> 3);
      int col = (lane & 7) * 8;
      gload_lds16(&A[(size_t)(m0 + row) * Kfull + k0 + col], &AsD[buf * 8192 + c * 512]);
      gload_lds16(&Bt[(size_t)(n0 + row) * Kfull + k0 + col], &BsD[buf * 8192 + c * 512]);
    }
  };

  int nT = Klen >> 6;
  STAGE(0, kbase);
  for (int tt = 0; tt < nT; ++tt) {
    int cur = tt & 1;
    if (tt + 1 < nT) {
      STAGE(cur ^ 1, kbase + (tt + 1) * 64);
      asm volatile("s_waitcnt vmcnt(8)" ::: "memory");  // tile tt landed; tt+1 in flight
    } else {
      asm volatile("s_waitcnt vmcnt(0)" ::: "memory");
    }
    __builtin_amdgcn_s_barrier();
    __builtin_amdgcn_sched_barrier(0);
    const bf16* As = &AsD[cur * 8192];
    const bf16* Bs = &BsD[cur * 8192];
#pragma unroll
    for (int kk = 0; kk < 2; ++kk) {
      bf16x8 af[4], bfr[4];
#pragma unroll
      for (int m = 0; m < 4; ++m)
        af[m] = *(const bf16x8*)&As[(wr * 64 + m * 16 + l15) * 64 + kk * 32 + l4 * 8];
#pragma unroll
      for (int n = 0; n < 4; ++n)
        bfr[n] = *(const bf16x8*)&Bs[(wc * 64 + n * 16 + l15) * 64 + kk * 32 + l4 * 8];
      __builtin_amdgcn_s_setprio(1);
#pragma unroll
      for (int m = 0; m < 4; ++m)
#pragma unroll
        for (int n = 0; n < 4; ++n)
          acc[m][n] = __builtin_amdgcn_mfma_f32_16x16x32_bf16(af[m], bfr[n], acc[m][n], 0, 0, 0);
      __builtin_amdgcn_s_setprio(0);
    }
    __builtin_amdgcn_s_barrier();  // all waves done reading [cur] before it's restaged
  }
  gemm_epilogue(acc, Cb, Cf, N, m0, n0);
}

// dual GEMM A, split-K=2 + prefetch: Xb @ {WqaT -> qa0/qa1 | WkvaT -> kvc0/kvc1}
__global__ __launch_bounds__(256) void k_gemm_a(const bf16* __restrict__ Xb,
                                                const bf16* __restrict__ B1, const bf16* __restrict__ B2,
                                                float* __restrict__ qa0, float* __restrict__ qa1,
                                                float* __restrict__ kvc0, float* __restrict__ kvc1) {
  __shared__ __align__(16) bf16 AsD[2 * 128 * 64];
  __shared__ __align__(16) bf16 BsD[2 * 128 * 64];
  int by = blockIdx.y;
  if (by < 24) {
    int yy = by >> 1, kh = by & 1;
    gemm_body_pf(Xb, B1, nullptr, kh ? qa1 : qa0, 1536, 2048, kh * 1024, 1024,
                 blockIdx.x * 128, yy * 128, AsD, BsD);
  } else {
    int r = by - 24, yy = r >> 1, kh = r & 1;
    gemm_body_pf(Xb, B2, nullptr, kh ? kvc1 : kvc0, 576, 2048, kh * 1024, 1024,
                 blockIdx.x * 128, yy * 128, AsD, BsD);
  }
}

// dual GEMM B (3.5 blocks/CU -> keep single-buffered body)
__global__ __launch_bounds__(256) void k_gemm_b(const bf16* __restrict__ A1, const bf16* __restrict__ A2,
                                                const bf16* __restrict__ B1, const bf16* __restrict__ B2,
                                                bf16* __restrict__ C1, bf16* __restrict__ C2) {
  __shared__ __align__(16) bf16 As[128 * 64];
  __shared__ __align__(16) bf16 Bs[128 * 64];
  int by = blockIdx.y;
  if (by < 24) gemm_body(A1, B1, C1, nullptr, 3072, 1536, 0, 1536, blockIdx.x * 128, by * 128, As, Bs);
  else         gemm_body(A2, B2, C2, nullptr, 4096, 512, 0, 512, blockIdx.x * 128, (by - 24) * 128, As, Bs);
}

// Wo GEMM, split-K=2 + prefetch -> fp32 partial halves
__global__ __launch_bounds__(256) void k_gemm_sk(const bf16* __restrict__ A, const bf16* __restrict__ Bt,
                                                 float* __restrict__ O0, float* __restrict__ O1) {
  __shared__ __align__(16) bf16 AsD[2 * 128 * 64];
  __shared__ __align__(16) bf16 BsD[2 * 128 * 64];
  int by = blockIdx.y, nt = by >> 1, kh = by & 1;
  gemm_body_pf(A, Bt, nullptr, kh ? O1 : O0, 2048, 2048, kh * 1024, 1024,
               blockIdx.x * 128, nt * 128, AsD, BsD);
}

// final add: out = O0 + O1 (float4)
__global__ void k_add(const float* __restrict__ O0, const float* __restrict__ O1,
                      float* __restrict__ out) {
  int base = (blockIdx.x * 256 + threadIdx.x) * 4;
  float4 a = *(const float4*)(O0 + base);
  float4 b = *(const float4*)(O1 + base);
  float4 o = { a.x + b.x, a.y + b.y, a.z + b.z, a.w + b.w };
  *(float4*)(out + base) = o;
}

// ================= merged RMSNorms (inputs = split-K partial sums) =================
__device__ inline float block_reduce_sum(float v, float* red) {
#pragma unroll
  for (int off = 1; off < 64; off <<= 1) v += __shfl_xor(v, off);
  int w = threadIdx.x >> 6;
  if ((threadIdx.x & 63) == 0) red[w] = v;
  __syncthreads();
  return red[0] + red[1] + red[2] + red[3];
}

__global__ void k_rms_all(const float* __restrict__ qa0, const float* __restrict__ qa1,
                          const float* __restrict__ gq, bf16* __restrict__ qc,
                          const float* __restrict__ kvc0, const float* __restrict__ kvc1,
                          const float* __restrict__ gkv,
                          bf16* __restrict__ kvn, bf16* __restrict__ kr) {
  __shared__ float red[4];
  int b = blockIdx.x, tid = threadIdx.x;
  if (b < 2048) {
    int row = b;
    float v[6];
    float ss = 0.f;
#pragma unroll
    for (int j = 0; j < 6; ++j) {
      size_t idx = (size_t)row * QL + tid + j * 256;
      v[j] = qa0[idx] + qa1[idx];
      ss += v[j] * v[j];
    }
    float tot = block_reduce_sum(ss, red);
    float rs = rsqrtf(tot / (float)QL + 1e-6f);
#pragma unroll
    for (int j = 0; j < 6; ++j) {
      int c = tid + j * 256;
      qc[(size_t)row * QL + c] = (bf16)(v[j] * rs * gq[c]);
    }
  } else {
    int row = b - 2048;
    size_t base = (size_t)row * 576;
    float v0 = kvc0[base + tid] + kvc1[base + tid];
    float v1 = kvc0[base + tid + 256] + kvc1[base + tid + 256];
    float tot = block_reduce_sum(v0 * v0 + v1 * v1, red);
    float rs = rsqrtf(tot / (float)KVL + 1e-6f);
    kvn[(size_t)row * KVL + tid] = (bf16)(v0 * rs * gkv[tid]);
    kvn[(size_t)row * KVL + tid + 256] = (bf16)(v1 * rs * gkv[tid + 256]);
    if (tid < 64) kr[row * 64 + tid] = (bf16)(kvc0[base + 512 + tid] + kvc1[base + 512 + tid]);
  }
}

// ================= V global transpose: VT[h][d][s] = KVm[s][h*256+128+d] =================
__global__ void k_vt(const bf16* __restrict__ KVm, bf16* __restrict__ VT) {
  __shared__ bf16 tile[32][34];
  int b = blockIdx.x, tid = threadIdx.x;
  int h = b >> 8, rem = b & 255;
  int d0 = (rem >> 6) * 32, s0 = (rem & 63) * 32;
  int cc = tid & 31, rr = tid >> 5;
#pragma unroll
  for (int it = 0; it < 4; ++it) {
    int r = it * 8 + rr;  // s-local
    tile[r][cc] = KVm[(size_t)(s0 + r) * 4096 + h * 256 + 128 + d0 + cc];
  }
  __syncthreads();
#pragma unroll
  for (int it = 0; it < 4; ++it) {
    int r = it * 8 + rr;  // d-local
    VT[((size_t)(h * 128 + d0 + r)) * 2048 + s0 + cc] = tile[cc][r];
  }
}

// ================= fused causal flash attention: dbuf prefetch + hoisted staging pointers =================
// grid 512: h = bid&15, qb pairing (i<16)?i:47-i, constant 33 tiles/CU.
// Staging source addresses are affine in t: precompute 10 per-thread pointers once,
// march by constant stride after each STAGE (stages run t=0,1,...,nt-1 strictly in
// order). Removes ~100 VALU/thread/tile of div/mod/select address math from the
// serial loop-top path. Extra ~28 VGPR is free: occupancy is LDS-capped (2 blk/CU).
__global__ __launch_bounds__(256) void k_attn(const bf16* __restrict__ Q, const bf16* __restrict__ KV,
                                              const bf16* __restrict__ KR, const bf16* __restrict__ VT,
                                              bf16* __restrict__ O) {
  __shared__ __align__(16) bf16 KsD[2][64 * 192];  // 2 x 24KB, linear+swz
  __shared__ __align__(16) bf16 VtD[2][128 * 64];  // 2 x 16KB, linear+swz
  int bid = blockIdx.x;
  int h = bid & 15, i = bid >> 4;
  int qb = (i < 16) ? i : 47 - i;
  int q0 = qb * 64;
  int tid = threadIdx.x, lane = tid & 63, w = tid >> 6;
  int l15 = lane & 15, l4 = lane >> 4;
  int sw = (l15 & 7) << 4;  // row-keyed byte-xor for swizzled reads
  const bf16* VTh = VT + (size_t)h * 128 * 2048;

  // Q fragments (B-operand: col=q=l15, k = ks*32 + l4*8 + j)
  bf16x8 aq[6];
  int qrow = q0 + w * 16 + l15;
#pragma unroll
  for (int ks = 0; ks < 6; ++ks)
    aq[ks] = *(const bf16x8*)&Q[(size_t)qrow * 3072 + h * 192 + ks * 32 + l4 * 8];

  // ---- hoisted staging pointers (per-thread, affine in t) ----
  const char* pK[6];
  unsigned stK[6];
#pragma unroll
  for (int it = 0; it < 6; ++it) {
    int idx = it * 256 + tid;
    int r = idx / 24, gg = idx - r * 24;
    int c = gg ^ (r & 7);  // gg<16 stays <16 (xor on low 3 bits)
    if (c < 16) { pK[it] = (const char*)&KV[(size_t)r * 4096 + h * 256 + c * 8]; stK[it] = 64 * 4096 * 2; }
    else        { pK[it] = (const char*)&KR[(size_t)r * 64 + (c - 16) * 8];      stK[it] = 64 * 64 * 2; }
  }
  const char* pV[4];
#pragma unroll
  for (int it = 0; it < 4; ++it) {
    int idx = it * 256 + tid;
    int d = idx >> 3, c2 = idx & 7, c = c2 ^ (d & 7);
    pV[it] = (const char*)&VTh[(size_t)d * 2048 + c * 8];
  }

  f32x4 oacc[8] = {};               // O^T: d = vf*16 + l4*4 + r, q = l15
  float mrun = -1e30f, lrun = 0.f;  // per-lane scalars (q = l15)
  int nt = qb + 1;

  // staging: reads current pointers, then advances them (calls are strictly t-ordered)
  auto STAGE = [&](int buf) {
    char* kb = (char*)KsD[buf];
    char* vb = (char*)VtD[buf];
#pragma unroll
    for (int it = 0; it < 6; ++it) {
      gload_lds16(pK[it], kb + (it * 256 + w * 64) * 16);
      pK[it] += stK[it];
    }
#pragma unroll
    for (int it = 0; it < 4; ++it) {
      gload_lds16(pV[it], vb + (it * 256 + w * 64) * 16);
      pV[it] += 64 * 2;
    }
  };

  STAGE(0);
  for (int t = 0; t < nt; ++t) {
    int cur = t & 1;
    if (t + 1 < nt) {
      STAGE(cur ^ 1);
      asm volatile("s_waitcnt vmcnt(10)" ::: "memory");
    } else {
      asm volatile("s_waitcnt vmcnt(0)" ::: "memory");
    }
    __builtin_amdgcn_s_barrier();
    __builtin_amdgcn_sched_barrier(0);
    const char* Kb = (const char*)KsD[cur];
    const char* Vb = (const char*)VtD[cur];

    // ---- S^T = K x Q ----
    f32x4 sacc[4] = {};
    __builtin_amdgcn_s_setprio(1);
#pragma unroll
    for (int ks = 0; ks < 6; ++ks) {
      int co = (((ks << 2) + l4) << 4) ^ sw;
#pragma unroll
      for (int n = 0; n < 4; ++n) {
        bf16x8 ak = *(const bf16x8*)(Kb + (n * 16 + l15) * 384 + co);
        sacc[n] = __builtin_amdgcn_mfma_f32_16x16x32_bf16(ak, aq[ks], sacc[n], 0, 0, 0);
      }
    }
    __builtin_amdgcn_s_setprio(0);

    // ---- scale + causal mask ----
    bool maskt = (t == qb);
#pragma unroll
    for (int n = 0; n < 4; ++n)
#pragma unroll
      for (int r = 0; r < 4; ++r) {
        float v = sacc[n][r] * SCALE_LOG2E;
        if (maskt) {
          int kvp = t * 64 + n * 16 + l4 * 4 + r;
          if (kvp > qrow) v = -1e30f;
        }
        sacc[n][r] = v;
      }

    // ---- per-lane softmax ----
    float mx = sacc[0][0];
#pragma unroll
    for (int n = 0; n < 4; ++n)
#pragma unroll
      for (int r = 0; r < 4; ++r) mx = fmaxf(mx, sacc[n][r]);
    mx = fmaxf(mx, __shfl_xor(mx, 16));
    mx = fmaxf(mx, __shfl_xor(mx, 32));
    if (__any(mx - mrun > 8.0f)) {  // defer-max (T13)
      float mn = fmaxf(mrun, mx);
      float al = fexp2(mrun - mn);
      mrun = mn;
      lrun *= al;
#pragma unroll
      for (int vf = 0; vf < 8; ++vf) oacc[vf] *= al;
    }
    float rsum = 0.f;
    unsigned pk[4][2];
#pragma unroll
    for (int n = 0; n < 4; ++n) {
      float e0 = fexp2(sacc[n][0] - mrun);
      float e1 = fexp2(sacc[n][1] - mrun);
      float e2 = fexp2(sacc[n][2] - mrun);
      float e3 = fexp2(sacc[n][3] - mrun);
      rsum += (e0 + e1) + (e2 + e3);
      pk[n][0] = cvt_pk_bf16(e0, e1);
      pk[n][1] = cvt_pk_bf16(e2, e3);
    }
    rsum += __shfl_xor(rsum, 16);
    rsum += __shfl_xor(rsum, 32);
    lrun += rsum;

    // ---- O^T += V^T x P^T; P B-operand rebuilt in-register via shfl ----
    int srcA = l15 + ((l4 & 1) << 5);
    int srcB = srcA + 16;
    int sel = l4 >> 1;
    __builtin_amdgcn_s_setprio(1);
#pragma unroll
    for (int ks = 0; ks < 2; ++ks) {
      unsigned a00 = (unsigned)__shfl((int)pk[2 * ks][0], srcA);
      unsigned a10 = (unsigned)__shfl((int)pk[2 * ks + 1][0], srcA);
      unsigned a01 = (unsigned)__shfl((int)pk[2 * ks][1], srcA);
      unsigned a11 = (unsigned)__shfl((int)pk[2 * ks + 1][1], srcA);
      unsigned b00 = (unsigned)__shfl((int)pk[2 * ks][0], srcB);
      unsigned b10 = (unsigned)__shfl((int)pk[2 * ks + 1][0], srcB);
      unsigned b01 = (unsigned)__shfl((int)pk[2 * ks][1], srcB);
      unsigned b11 = (unsigned)__shfl((int)pk[2 * ks + 1][1], srcB);
      union { unsigned u[4]; bf16x8 v; } ap;
      ap.u[0] = sel ? a10 : a00;
      ap.u[1] = sel ? a11 : a01;
      ap.u[2] = sel ? b10 : b00;
      ap.u[3] = sel ? b11 : b01;
      int co = (((ks << 2) + l4) << 4) ^ sw;
#pragma unroll
      for (int vf = 0; vf < 8; ++vf) {
        bf16x8 av = *(const bf16x8*)(Vb + (vf * 16 + l15) * 128 + co);
        oacc[vf] = __builtin_amdgcn_mfma_f32_16x16x32_bf16(av, ap.v, oacc[vf], 0, 0, 0);
      }
    }
    __builtin_amdgcn_s_setprio(0);
    __builtin_amdgcn_s_barrier();
  }

  // ---- epilogue: normalize, transpose O^T -> O via just-read K buffer ----
  int curF = (nt - 1) & 1;
  char* OTw = (char*)KsD[curF] + w * 4096;
  float inv = 1.0f / lrun;
#pragma unroll
  for (int vf = 0; vf < 8; ++vf) {
    unsigned ua = cvt_pk_bf16(oacc[vf][0] * inv, oacc[vf][1] * inv);
    unsigned ub = cvt_pk_bf16(oacc[vf][2] * inv, oacc[vf][3] * inv);
    int base = vf * 32 + l4 * 8;
    *(unsigned*)(OTw + l15 * 256 + ((base + 0) ^ sw)) = ua;
    *(unsigned*)(OTw + l15 * 256 + ((base + 4) ^ sw)) = ub;
  }
  int qq = lane >> 2, c0 = lane & 3;
  size_t obase = (size_t)(q0 + w * 16 + qq) * 2048 + h * 128;
#pragma unroll
  for (int ii = 0; ii < 4; ++ii) {
    int ck = ii * 4 + c0;
    bf16x8 v = *(const bf16x8*)(OTw + qq * 256 + ((ck * 16) ^ ((qq & 7) << 4)));
    *(bf16x8*)&O[obase + ck * 8] = v;
  }
}

extern "C" void kernel_launch(void* const* d_in, const int* in_sizes, int n_in,
                              void* d_out, int out_size, void* d_ws, size_t ws_size,
                              hipStream_t stream) {
  (void)in_sizes; (void)n_in; (void)out_size; (void)ws_size;
  const float* hidden = (const float*)d_in[0];
  const float* Wqa  = (const float*)d_in[2];
  const float* gqa  = (const float*)d_in[3];
  const float* Wqb  = (const float*)d_in[4];
  const float* Wkva = (const float*)d_in[5];
  const float* gkva = (const float*)d_in[6];
  const float* Wkvb = (const float*)d_in[7];
  const float* Wo   = (const float*)d_in[8];
  float* out = (float*)d_out;

  char* ws = (char*)d_ws;
  size_t off = 0;
  auto alloc = [&](size_t bytes) {
    char* p = ws + off;
    off += (bytes + 255) & ~(size_t)255;
    return p;
  };
  bf16* Xb     = (bf16*)alloc((size_t)SEQ * HIDDEN * 2);
  bf16* WqaT   = (bf16*)alloc((size_t)QL * HIDDEN * 2);
  bf16* WqbT   = (bf16*)alloc((size_t)3072 * QL * 2);
  bf16* WkvaT  = (bf16*)alloc((size_t)576 * HIDDEN * 2);
  bf16* WkvbT  = (bf16*)alloc((size_t)4096 * KVL * 2);
  bf16* WoT    = (bf16*)alloc((size_t)2048 * 2048 * 2);
  float* qa0   = (float*)alloc((size_t)SEQ * QL * 4);
  float* qa1   = (float*)alloc((size_t)SEQ * QL * 4);
  float* kvc0  = (float*)alloc((size_t)SEQ * 576 * 4);
  float* kvc1  = (float*)alloc((size_t)SEQ * 576 * 4);
  bf16* qc     = (bf16*)alloc((size_t)SEQ * QL * 2);
  bf16* kvn    = (bf16*)alloc((size_t)SEQ * KVL * 2);
  bf16* krope  = (bf16*)alloc((size_t)SEQ * 64 * 2);
  bf16* Qm     = (bf16*)alloc((size_t)SEQ * 3072 * 2);
  bf16* KVm    = (bf16*)alloc((size_t)SEQ * 4096 * 2);
  bf16* VTg    = (bf16*)alloc((size_t)NH * 128 * SEQ * 2);
  bf16* Om     = (bf16*)alloc((size_t)SEQ * 2048 * 2);
  // Wo split-K partials alias buffers dead after attn
  float* O0 = qa0;
  float* O1 = (float*)KVm;

  k_prep<<<19072, 256, 0, stream>>>(hidden, Xb, Wqa, WqaT, Wqb, WqbT,
                                    Wkva, WkvaT, Wkvb, WkvbT, Wo, WoT);
  k_gemm_a<<<dim3(16, 34), 256, 0, stream>>>(Xb, WqaT, WkvaT, qa0, qa1, kvc0, kvc1);
  k_rms_all<<<4096, 256, 0, stream>>>(qa0, qa1, gqa, qc, kvc0, kvc1, gkva, kvn, krope);
  k_gemm_b<<<dim3(16, 56), 256, 0, stream>>>(qc, kvn, WqbT, WkvbT, Qm, KVm);
  k_vt<<<4096, 256, 0, stream>>>(KVm, VTg);
  k_attn<<<512, 256, 0, stream>>>(Qm, KVm, krope, VTg, Om);
  k_gemm_sk<<<dim3(16, 32), 256, 0, stream>>>(Om, WoT, O0, O1);
  k_add<<<4096, 256, 0, stream>>>(O0, O1, out);
}

// Round 18
// 203.929 us; speedup vs baseline: 1.0331x; 1.0331x over previous
//
#include <hip/hip_runtime.h>
#include <hip/hip_bf16.h>

typedef __bf16 bf16;
typedef __bf16 bf16x8 __attribute__((ext_vector_type(8)));
typedef __bf16 bf16x4 __attribute__((ext_vector_type(4)));
typedef float f32x4 __attribute__((ext_vector_type(4)));

#define HIDDEN 2048
#define SEQ 2048
#define NH 16
#define QL 1536
#define KVL 512
// 1/sqrt(192) * log2(e)
#define SCALE_LOG2E 0.10411754631f

// ---- global -> LDS direct load, 16B per lane. Dest = wave-uniform base + lane*16. ----
__device__ __forceinline__ void gload_lds16(const void* g, void* l) {
  typedef const __attribute__((address_space(1))) void* gp_t;
  typedef __attribute__((address_space(3))) void* lp_t;
  __builtin_amdgcn_global_load_lds((gp_t)(unsigned long long)g,
                                   (lp_t)(unsigned int)(unsigned long long)l, 16, 0, 0);
}

// raw v_exp_f32: computes 2^x
__device__ __forceinline__ float fexp2(float x) {
  float r; asm("v_exp_f32 %0, %1" : "=v"(r) : "v"(x)); return r;
}
// pack 2 f32 -> 2 bf16 in one u32 (low = lo)
__device__ __forceinline__ unsigned cvt_pk_bf16(float lo, float hi) {
  unsigned r; asm("v_cvt_pk_bf16_f32 %0, %1, %2" : "=v"(r) : "v"(lo), "v"(hi)); return r;
}

// ================= prep: 5 weight transposes (fp32[K][N] -> bf16[N][K]) + hidden cvt =================
__global__ void k_prep(const float* __restrict__ hidden, bf16* __restrict__ Xb,
                       const float* __restrict__ Wqa, bf16* __restrict__ WqaT,
                       const float* __restrict__ Wqb, bf16* __restrict__ WqbT,
                       const float* __restrict__ Wkva, bf16* __restrict__ WkvaT,
                       const float* __restrict__ Wkvb, bf16* __restrict__ WkvbT,
                       const float* __restrict__ Wo, bf16* __restrict__ WoT) {
  __shared__ float tile[32][33];
  int b = blockIdx.x, tid = threadIdx.x;
  const float* W; bf16* Wt; int K, N, bx, by;
  if (b < 3072)       { W = Wqa;  Wt = WqaT;  K = 2048; N = 1536; int r = b;         bx = r % 48;  by = r / 48; }
  else if (b < 7680)  { W = Wqb;  Wt = WqbT;  K = 1536; N = 3072; int r = b - 3072;  bx = r % 96;  by = r / 96; }
  else if (b < 8832)  { W = Wkva; Wt = WkvaT; K = 2048; N = 576;  int r = b - 7680;  bx = r % 18;  by = r / 18; }
  else if (b < 10880) { W = Wkvb; Wt = WkvbT; K = 512;  N = 4096; int r = b - 8832;  bx = r % 128; by = r / 128; }
  else if (b < 14976) { W = Wo;   Wt = WoT;   K = 2048; N = 2048; int r = b - 10880; bx = r % 64;  by = r / 64; }
  else {
    int r = b - 14976;
    int base = (r * 256 + tid) * 4;
    float4 v = *(const float4*)(hidden + base);
    bf16x4 o = { (bf16)v.x, (bf16)v.y, (bf16)v.z, (bf16)v.w };
    *(bf16x4*)(Xb + base) = o;
    return;
  }
  int n0 = bx * 32, k0 = by * 32, cc = tid & 31, rr = tid >> 5;
#pragma unroll
  for (int it = 0; it < 4; ++it) {
    int r = it * 8 + rr;
    tile[r][cc] = W[(size_t)(k0 + r) * N + n0 + cc];
  }
  __syncthreads();
#pragma unroll
  for (int it = 0; it < 4; ++it) {
    int r = it * 8 + rr;
    Wt[(size_t)(n0 + r) * K + k0 + cc] = (bf16)tile[cc][r];
  }
}

// ================= GEMM epilogue (shared) =================
__device__ __forceinline__ void gemm_epilogue(f32x4 acc[4][4], bf16* Cb, float* Cf,
                                              int N, int m0, int n0) {
  int lane = threadIdx.x & 63, w = threadIdx.x >> 6;
  int wr = w >> 1, wc = w & 1;
  int l15 = lane & 15, l4 = lane >> 4;
#pragma unroll
  for (int m = 0; m < 4; ++m)
#pragma unroll
    for (int n = 0; n < 4; ++n)
#pragma unroll
      for (int r = 0; r < 4; ++r) {
        int grow = m0 + wr * 64 + m * 16 + l4 * 4 + r;
        int gcol = n0 + wc * 64 + n * 16 + l15;
        if (gcol < N) {
          float v = acc[m][n][r];
          if (Cf) Cf[(size_t)grow * N + gcol] = v;
          else Cb[(size_t)grow * N + gcol] = (bf16)v;
        }
      }
}

// ================= GEMM body (m97 structure, single-buffered) — for well-occupied grids =================
__device__ __forceinline__ void gemm_body(const bf16* __restrict__ A, const bf16* __restrict__ Bt,
                                          bf16* __restrict__ Cb, float* __restrict__ Cf,
                                          int N, int Kfull, int kbase, int Klen,
                                          int m0, int n0, bf16* As, bf16* Bs) {
  int tid = threadIdx.x, lane = tid & 63, w = tid >> 6;
  int wr = w >> 1, wc = w & 1;
  int l15 = lane & 15, l4 = lane >> 4;
  f32x4 acc[4][4] = {};
  for (int k0 = kbase; k0 < kbase + Klen; k0 += 64) {
#pragma unroll
    for (int i = 0; i < 4; ++i) {
      int c = w * 4 + i;
      int row = c * 8 + (lane >> 3);
      int col = (lane & 7) * 8;
      gload_lds16(&A[(size_t)(m0 + row) * Kfull + k0 + col], &As[c * 512]);
      gload_lds16(&Bt[(size_t)(n0 + row) * Kfull + k0 + col], &Bs[c * 512]);
    }
    __syncthreads();
#pragma unroll
    for (int kk = 0; kk < 2; ++kk) {
      bf16x8 af[4], bfr[4];
#pragma unroll
      for (int m = 0; m < 4; ++m)
        af[m] = *(const bf16x8*)&As[(wr * 64 + m * 16 + l15) * 64 + kk * 32 + l4 * 8];
#pragma unroll
      for (int n = 0; n < 4; ++n)
        bfr[n] = *(const bf16x8*)&Bs[(wc * 64 + n * 16 + l15) * 64 + kk * 32 + l4 * 8];
      __builtin_amdgcn_s_setprio(1);
#pragma unroll
      for (int m = 0; m < 4; ++m)
#pragma unroll
        for (int n = 0; n < 4; ++n)
          acc[m][n] = __builtin_amdgcn_mfma_f32_16x16x32_bf16(af[m], bfr[n], acc[m][n], 0, 0, 0);
      __builtin_amdgcn_s_setprio(0);
    }
    __syncthreads();
  }
  gemm_epilogue(acc, Cb, Cf, N, m0, n0);
}

// ================= GEMM body, double-buffered prefetch (T3-min) — for grid-starved kernels =================
__device__ __forceinline__ void gemm_body_pf(const bf16* __restrict__ A, const bf16* __restrict__ Bt,
                                             bf16* __restrict__ Cb, float* __restrict__ Cf,
                                             int N, int Kfull, int kbase, int Klen,
                                             int m0, int n0, bf16* AsD, bf16* BsD) {
  int tid = threadIdx.x, lane = tid & 63, w = tid >> 6;
  int wr = w >> 1, wc = w & 1;
  int l15 = lane & 15, l4 = lane >> 4;
  f32x4 acc[4][4] = {};

  auto STAGE = [&](int buf, int k0) {
#pragma unroll
    for (int i = 0; i < 4; ++i) {
      int c = w * 4 + i;
      int row = c * 8 + (lane >> 3);
      int col = (lane & 7) * 8;
      gload_lds16(&A[(size_t)(m0 + row) * Kfull + k0 + col], &AsD[buf * 8192 + c * 512]);
      gload_lds16(&Bt[(size_t)(n0 + row) * Kfull + k0 + col], &BsD[buf * 8192 + c * 512]);
    }
  };

  int nT = Klen >> 6;
  STAGE(0, kbase);
  for (int tt = 0; tt < nT; ++tt) {
    int cur = tt & 1;
    if (tt + 1 < nT) {
      STAGE(cur ^ 1, kbase + (tt + 1) * 64);
      asm volatile("s_waitcnt vmcnt(8)" ::: "memory");  // tile tt landed; tt+1 in flight
    } else {
      asm volatile("s_waitcnt vmcnt(0)" ::: "memory");
    }
    __builtin_amdgcn_s_barrier();
    __builtin_amdgcn_sched_barrier(0);
    const bf16* As = &AsD[cur * 8192];
    const bf16* Bs = &BsD[cur * 8192];
#pragma unroll
    for (int kk = 0; kk < 2; ++kk) {
      bf16x8 af[4], bfr[4];
#pragma unroll
      for (int m = 0; m < 4; ++m)
        af[m] = *(const bf16x8*)&As[(wr * 64 + m * 16 + l15) * 64 + kk * 32 + l4 * 8];
#pragma unroll
      for (int n = 0; n < 4; ++n)
        bfr[n] = *(const bf16x8*)&Bs[(wc * 64 + n * 16 + l15) * 64 + kk * 32 + l4 * 8];
      __builtin_amdgcn_s_setprio(1);
#pragma unroll
      for (int m = 0; m < 4; ++m)
#pragma unroll
        for (int n = 0; n < 4; ++n)
          acc[m][n] = __builtin_amdgcn_mfma_f32_16x16x32_bf16(af[m], bfr[n], acc[m][n], 0, 0, 0);
      __builtin_amdgcn_s_setprio(0);
    }
    __builtin_amdgcn_s_barrier();  // all waves done reading [cur] before it's restaged
  }
  gemm_epilogue(acc, Cb, Cf, N, m0, n0);
}

// dual GEMM A, split-K=2 + prefetch: Xb @ {WqaT -> qa0/qa1 | WkvaT -> kvc0/kvc1}
__global__ __launch_bounds__(256) void k_gemm_a(const bf16* __restrict__ Xb,
                                                const bf16* __restrict__ B1, const bf16* __restrict__ B2,
                                                float* __restrict__ qa0, float* __restrict__ qa1,
                                                float* __restrict__ kvc0, float* __restrict__ kvc1) {
  __shared__ __align__(16) bf16 AsD[2 * 128 * 64];
  __shared__ __align__(16) bf16 BsD[2 * 128 * 64];
  int by = blockIdx.y;
  if (by < 24) {
    int yy = by >> 1, kh = by & 1;
    gemm_body_pf(Xb, B1, nullptr, kh ? qa1 : qa0, 1536, 2048, kh * 1024, 1024,
                 blockIdx.x * 128, yy * 128, AsD, BsD);
  } else {
    int r = by - 24, yy = r >> 1, kh = r & 1;
    gemm_body_pf(Xb, B2, nullptr, kh ? kvc1 : kvc0, 576, 2048, kh * 1024, 1024,
                 blockIdx.x * 128, yy * 128, AsD, BsD);
  }
}

// dual GEMM B (3.5 blocks/CU -> keep single-buffered body)
__global__ __launch_bounds__(256) void k_gemm_b(const bf16* __restrict__ A1, const bf16* __restrict__ A2,
                                                const bf16* __restrict__ B1, const bf16* __restrict__ B2,
                                                bf16* __restrict__ C1, bf16* __restrict__ C2) {
  __shared__ __align__(16) bf16 As[128 * 64];
  __shared__ __align__(16) bf16 Bs[128 * 64];
  int by = blockIdx.y;
  if (by < 24) gemm_body(A1, B1, C1, nullptr, 3072, 1536, 0, 1536, blockIdx.x * 128, by * 128, As, Bs);
  else         gemm_body(A2, B2, C2, nullptr, 4096, 512, 0, 512, blockIdx.x * 128, (by - 24) * 128, As, Bs);
}

// Wo GEMM, split-K=2 + prefetch -> fp32 partial halves
__global__ __launch_bounds__(256) void k_gemm_sk(const bf16* __restrict__ A, const bf16* __restrict__ Bt,
                                                 float* __restrict__ O0, float* __restrict__ O1) {
  __shared__ __align__(16) bf16 AsD[2 * 128 * 64];
  __shared__ __align__(16) bf16 BsD[2 * 128 * 64];
  int by = blockIdx.y, nt = by >> 1, kh = by & 1;
  gemm_body_pf(A, Bt, nullptr, kh ? O1 : O0, 2048, 2048, kh * 1024, 1024,
               blockIdx.x * 128, nt * 128, AsD, BsD);
}

// final add: out = O0 + O1 (float4)
__global__ void k_add(const float* __restrict__ O0, const float* __restrict__ O1,
                      float* __restrict__ out) {
  int base = (blockIdx.x * 256 + threadIdx.x) * 4;
  float4 a = *(const float4*)(O0 + base);
  float4 b = *(const float4*)(O1 + base);
  float4 o = { a.x + b.x, a.y + b.y, a.z + b.z, a.w + b.w };
  *(float4*)(out + base) = o;
}

// ================= merged RMSNorms (inputs = split-K partial sums) =================
__device__ inline float block_reduce_sum(float v, float* red) {
#pragma unroll
  for (int off = 1; off < 64; off <<= 1) v += __shfl_xor(v, off);
  int w = threadIdx.x >> 6;
  if ((threadIdx.x & 63) == 0) red[w] = v;
  __syncthreads();
  return red[0] + red[1] + red[2] + red[3];
}

__global__ void k_rms_all(const float* __restrict__ qa0, const float* __restrict__ qa1,
                          const float* __restrict__ gq, bf16* __restrict__ qc,
                          const float* __restrict__ kvc0, const float* __restrict__ kvc1,
                          const float* __restrict__ gkv,
                          bf16* __restrict__ kvn, bf16* __restrict__ kr) {
  __shared__ float red[4];
  int b = blockIdx.x, tid = threadIdx.x;
  if (b < 2048) {
    int row = b;
    float v[6];
    float ss = 0.f;
#pragma unroll
    for (int j = 0; j < 6; ++j) {
      size_t idx = (size_t)row * QL + tid + j * 256;
      v[j] = qa0[idx] + qa1[idx];
      ss += v[j] * v[j];
    }
    float tot = block_reduce_sum(ss, red);
    float rs = rsqrtf(tot / (float)QL + 1e-6f);
#pragma unroll
    for (int j = 0; j < 6; ++j) {
      int c = tid + j * 256;
      qc[(size_t)row * QL + c] = (bf16)(v[j] * rs * gq[c]);
    }
  } else {
    int row = b - 2048;
    size_t base = (size_t)row * 576;
    float v0 = kvc0[base + tid] + kvc1[base + tid];
    float v1 = kvc0[base + tid + 256] + kvc1[base + tid + 256];
    float tot = block_reduce_sum(v0 * v0 + v1 * v1, red);
    float rs = rsqrtf(tot / (float)KVL + 1e-6f);
    kvn[(size_t)row * KVL + tid] = (bf16)(v0 * rs * gkv[tid]);
    kvn[(size_t)row * KVL + tid + 256] = (bf16)(v1 * rs * gkv[tid + 256]);
    if (tid < 64) kr[row * 64 + tid] = (bf16)(kvc0[base + 512 + tid] + kvc1[base + 512 + tid]);
  }
}

// ================= V global transpose: VT[h][d][s] = KVm[s][h*256+128+d] =================
__global__ void k_vt(const bf16* __restrict__ KVm, bf16* __restrict__ VT) {
  __shared__ bf16 tile[32][34];
  int b = blockIdx.x, tid = threadIdx.x;
  int h = b >> 8, rem = b & 255;
  int d0 = (rem >> 6) * 32, s0 = (rem & 63) * 32;
  int cc = tid & 31, rr = tid >> 5;
#pragma unroll
  for (int it = 0; it < 4; ++it) {
    int r = it * 8 + rr;  // s-local
    tile[r][cc] = KVm[(size_t)(s0 + r) * 4096 + h * 256 + 128 + d0 + cc];
  }
  __syncthreads();
#pragma unroll
  for (int it = 0; it < 4; ++it) {
    int r = it * 8 + rr;  // d-local
    VT[((size_t)(h * 128 + d0 + r)) * 2048 + s0 + cc] = tile[cc][r];
  }
}

// ================= fused causal flash attention: double-buffered prefetch (session best) =================
// grid 512: h = bid&15, qb pairing (i<16)?i:47-i — CU c hosts blocks c and c+256,
// constant 33 tiles/CU. 4 waves x 16 q-rows, KVBLK=64, K/V double-buffered (80KB).
// Per-tile addressing left to the compiler: R17 proved hoisted pointers regress
// (address VALU was already hidden; extra live state hurt scheduling).
__global__ __launch_bounds__(256) void k_attn(const bf16* __restrict__ Q, const bf16* __restrict__ KV,
                                              const bf16* __restrict__ KR, const bf16* __restrict__ VT,
                                              bf16* __restrict__ O) {
  __shared__ __align__(16) bf16 KsD[2][64 * 192];  // 2 x 24KB, linear+swz
  __shared__ __align__(16) bf16 VtD[2][128 * 64];  // 2 x 16KB, linear+swz
  int bid = blockIdx.x;
  int h = bid & 15, i = bid >> 4;
  int qb = (i < 16) ? i : 47 - i;
  int q0 = qb * 64;
  int tid = threadIdx.x, lane = tid & 63, w = tid >> 6;
  int l15 = lane & 15, l4 = lane >> 4;
  int sw = (l15 & 7) << 4;  // row-keyed byte-xor for swizzled reads
  const bf16* VTh = VT + (size_t)h * 128 * 2048;

  // Q fragments (B-operand: col=q=l15, k = ks*32 + l4*8 + j)
  bf16x8 aq[6];
  int qrow = q0 + w * 16 + l15;
#pragma unroll
  for (int ks = 0; ks < 6; ++ks)
    aq[ks] = *(const bf16x8*)&Q[(size_t)qrow * 3072 + h * 192 + ks * 32 + l4 * 8];

  f32x4 oacc[8] = {};               // O^T: d = vf*16 + l4*4 + r, q = l15
  float mrun = -1e30f, lrun = 0.f;  // per-lane scalars (q = l15)
  int nt = qb + 1;

  auto STAGE = [&](int buf, int t) {
    char* kb = (char*)KsD[buf];
    char* vb = (char*)VtD[buf];
#pragma unroll
    for (int it = 0; it < 6; ++it) {
      int idx = it * 256 + tid;
      int r = idx / 24, gg = idx - r * 24;
      int c = gg ^ (r & 7);
      const bf16* src = (c < 16) ? &KV[(size_t)(t * 64 + r) * 4096 + h * 256 + c * 8]
                                 : &KR[(size_t)(t * 64 + r) * 64 + (c - 16) * 8];
      gload_lds16(src, kb + (it * 256 + w * 64) * 16);
    }
#pragma unroll
    for (int it = 0; it < 4; ++it) {
      int idx = it * 256 + tid;
      int d = idx >> 3, c2 = idx & 7, c = c2 ^ (d & 7);
      gload_lds16(&VTh[(size_t)d * 2048 + t * 64 + c * 8], vb + (it * 256 + w * 64) * 16);
    }
  };

  STAGE(0, 0);
  for (int t = 0; t < nt; ++t) {
    int cur = t & 1;
    if (t + 1 < nt) {
      STAGE(cur ^ 1, t + 1);
      asm volatile("s_waitcnt vmcnt(10)" ::: "memory");
    } else {
      asm volatile("s_waitcnt vmcnt(0)" ::: "memory");
    }
    __builtin_amdgcn_s_barrier();
    __builtin_amdgcn_sched_barrier(0);
    const char* Kb = (const char*)KsD[cur];
    const char* Vb = (const char*)VtD[cur];

    // ---- S^T = K x Q ----
    f32x4 sacc[4] = {};
    __builtin_amdgcn_s_setprio(1);
#pragma unroll
    for (int ks = 0; ks < 6; ++ks) {
      int co = (((ks << 2) + l4) << 4) ^ sw;
#pragma unroll
      for (int n = 0; n < 4; ++n) {
        bf16x8 ak = *(const bf16x8*)(Kb + (n * 16 + l15) * 384 + co);
        sacc[n] = __builtin_amdgcn_mfma_f32_16x16x32_bf16(ak, aq[ks], sacc[n], 0, 0, 0);
      }
    }
    __builtin_amdgcn_s_setprio(0);

    // ---- scale + causal mask ----
    bool maskt = (t == qb);
#pragma unroll
    for (int n = 0; n < 4; ++n)
#pragma unroll
      for (int r = 0; r < 4; ++r) {
        float v = sacc[n][r] * SCALE_LOG2E;
        if (maskt) {
          int kvp = t * 64 + n * 16 + l4 * 4 + r;
          if (kvp > qrow) v = -1e30f;
        }
        sacc[n][r] = v;
      }

    // ---- per-lane softmax ----
    float mx = sacc[0][0];
#pragma unroll
    for (int n = 0; n < 4; ++n)
#pragma unroll
      for (int r = 0; r < 4; ++r) mx = fmaxf(mx, sacc[n][r]);
    mx = fmaxf(mx, __shfl_xor(mx, 16));
    mx = fmaxf(mx, __shfl_xor(mx, 32));
    if (__any(mx - mrun > 8.0f)) {  // defer-max (T13)
      float mn = fmaxf(mrun, mx);
      float al = fexp2(mrun - mn);
      mrun = mn;
      lrun *= al;
#pragma unroll
      for (int vf = 0; vf < 8; ++vf) oacc[vf] *= al;
    }
    float rsum = 0.f;
    unsigned pk[4][2];
#pragma unroll
    for (int n = 0; n < 4; ++n) {
      float e0 = fexp2(sacc[n][0] - mrun);
      float e1 = fexp2(sacc[n][1] - mrun);
      float e2 = fexp2(sacc[n][2] - mrun);
      float e3 = fexp2(sacc[n][3] - mrun);
      rsum += (e0 + e1) + (e2 + e3);
      pk[n][0] = cvt_pk_bf16(e0, e1);
      pk[n][1] = cvt_pk_bf16(e2, e3);
    }
    rsum += __shfl_xor(rsum, 16);
    rsum += __shfl_xor(rsum, 32);
    lrun += rsum;

    // ---- O^T += V^T x P^T; P B-operand rebuilt in-register via shfl ----
    int srcA = l15 + ((l4 & 1) << 5);
    int srcB = srcA + 16;
    int sel = l4 >> 1;
    __builtin_amdgcn_s_setprio(1);
#pragma unroll
    for (int ks = 0; ks < 2; ++ks) {
      unsigned a00 = (unsigned)__shfl((int)pk[2 * ks][0], srcA);
      unsigned a10 = (unsigned)__shfl((int)pk[2 * ks + 1][0], srcA);
      unsigned a01 = (unsigned)__shfl((int)pk[2 * ks][1], srcA);
      unsigned a11 = (unsigned)__shfl((int)pk[2 * ks + 1][1], srcA);
      unsigned b00 = (unsigned)__shfl((int)pk[2 * ks][0], srcB);
      unsigned b10 = (unsigned)__shfl((int)pk[2 * ks + 1][0], srcB);
      unsigned b01 = (unsigned)__shfl((int)pk[2 * ks][1], srcB);
      unsigned b11 = (unsigned)__shfl((int)pk[2 * ks + 1][1], srcB);
      union { unsigned u[4]; bf16x8 v; } ap;
      ap.u[0] = sel ? a10 : a00;
      ap.u[1] = sel ? a11 : a01;
      ap.u[2] = sel ? b10 : b00;
      ap.u[3] = sel ? b11 : b01;
      int co = (((ks << 2) + l4) << 4) ^ sw;
#pragma unroll
      for (int vf = 0; vf < 8; ++vf) {
        bf16x8 av = *(const bf16x8*)(Vb + (vf * 16 + l15) * 128 + co);
        oacc[vf] = __builtin_amdgcn_mfma_f32_16x16x32_bf16(av, ap.v, oacc[vf], 0, 0, 0);
      }
    }
    __builtin_amdgcn_s_setprio(0);
    __builtin_amdgcn_s_barrier();
  }

  // ---- epilogue: normalize, transpose O^T -> O via just-read K buffer ----
  int curF = (nt - 1) & 1;
  char* OTw = (char*)KsD[curF] + w * 4096;
  float inv = 1.0f / lrun;
#pragma unroll
  for (int vf = 0; vf < 8; ++vf) {
    unsigned ua = cvt_pk_bf16(oacc[vf][0] * inv, oacc[vf][1] * inv);
    unsigned ub = cvt_pk_bf16(oacc[vf][2] * inv, oacc[vf][3] * inv);
    int base = vf * 32 + l4 * 8;
    *(unsigned*)(OTw + l15 * 256 + ((base + 0) ^ sw)) = ua;
    *(unsigned*)(OTw + l15 * 256 + ((base + 4) ^ sw)) = ub;
  }
  int qq = lane >> 2, c0 = lane & 3;
  size_t obase = (size_t)(q0 + w * 16 + qq) * 2048 + h * 128;
#pragma unroll
  for (int ii = 0; ii < 4; ++ii) {
    int ck = ii * 4 + c0;
    bf16x8 v = *(const bf16x8*)(OTw + qq * 256 + ((ck * 16) ^ ((qq & 7) << 4)));
    *(bf16x8*)&O[obase + ck * 8] = v;
  }
}

extern "C" void kernel_launch(void* const* d_in, const int* in_sizes, int n_in,
                              void* d_out, int out_size, void* d_ws, size_t ws_size,
                              hipStream_t stream) {
  (void)in_sizes; (void)n_in; (void)out_size; (void)ws_size;
  const float* hidden = (const float*)d_in[0];
  const float* Wqa  = (const float*)d_in[2];
  const float* gqa  = (const float*)d_in[3];
  const float* Wqb  = (const float*)d_in[4];
  const float* Wkva = (const float*)d_in[5];
  const float* gkva = (const float*)d_in[6];
  const float* Wkvb = (const float*)d_in[7];
  const float* Wo   = (const float*)d_in[8];
  float* out = (float*)d_out;

  char* ws = (char*)d_ws;
  size_t off = 0;
  auto alloc = [&](size_t bytes) {
    char* p = ws + off;
    off += (bytes + 255) & ~(size_t)255;
    return p;
  };
  bf16* Xb     = (bf16*)alloc((size_t)SEQ * HIDDEN * 2);
  bf16* WqaT   = (bf16*)alloc((size_t)QL * HIDDEN * 2);
  bf16* WqbT   = (bf16*)alloc((size_t)3072 * QL * 2);
  bf16* WkvaT  = (bf16*)alloc((size_t)576 * HIDDEN * 2);
  bf16* WkvbT  = (bf16*)alloc((size_t)4096 * KVL * 2);
  bf16* WoT    = (bf16*)alloc((size_t)2048 * 2048 * 2);
  float* qa0   = (float*)alloc((size_t)SEQ * QL * 4);
  float* qa1   = (float*)alloc((size_t)SEQ * QL * 4);
  float* kvc0  = (float*)alloc((size_t)SEQ * 576 * 4);
  float* kvc1  = (float*)alloc((size_t)SEQ * 576 * 4);
  bf16* qc     = (bf16*)alloc((size_t)SEQ * QL * 2);
  bf16* kvn    = (bf16*)alloc((size_t)SEQ * KVL * 2);
  bf16* krope  = (bf16*)alloc((size_t)SEQ * 64 * 2);
  bf16* Qm     = (bf16*)alloc((size_t)SEQ * 3072 * 2);
  bf16* KVm    = (bf16*)alloc((size_t)SEQ * 4096 * 2);
  bf16* VTg    = (bf16*)alloc((size_t)NH * 128 * SEQ * 2);
  bf16* Om     = (bf16*)alloc((size_t)SEQ * 2048 * 2);
  // Wo split-K partials alias buffers dead after attn
  float* O0 = qa0;
  float* O1 = (float*)KVm;

  k_prep<<<19072, 256, 0, stream>>>(hidden, Xb, Wqa, WqaT, Wqb, WqbT,
                                    Wkva, WkvaT, Wkvb, WkvbT, Wo, WoT);
  k_gemm_a<<<dim3(16, 34), 256, 0, stream>>>(Xb, WqaT, WkvaT, qa0, qa1, kvc0, kvc1);
  k_rms_all<<<4096, 256, 0, stream>>>(qa0, qa1, gqa, qc, kvc0, kvc1, gkva, kvn, krope);
  k_gemm_b<<<dim3(16, 56), 256, 0, stream>>>(qc, kvn, WqbT, WkvbT, Qm, KVm);
  k_vt<<<4096, 256, 0, stream>>>(KVm, VTg);
  k_attn<<<512, 256, 0, stream>>>(Qm, KVm, krope, VTg, Om);
  k_gemm_sk<<<dim3(16, 32), 256, 0, stream>>>(Om, WoT, O0, O1);
  k_add<<<4096, 256, 0, stream>>>(O0, O1, out);
}